// Round 19
// baseline (161.911 us; speedup 1.0000x reference)
//
#include <hip/hip_runtime.h>

typedef unsigned short u16;
typedef unsigned int u32;
typedef __attribute__((ext_vector_type(8))) short s16x8;   // 8 bf16 (4 VGPR) MFMA frag
typedef __attribute__((ext_vector_type(4))) float f32x4;
typedef __attribute__((ext_vector_type(4))) u32 u32x4;
typedef __attribute__((ext_vector_type(4))) float fvec4;

#define DEV static __device__ __forceinline__

typedef __attribute__((address_space(1))) unsigned char ga_u8;
typedef __attribute__((address_space(3))) unsigned char la_u8;

DEV u16 f2bf(float f){
  u32 u = __builtin_bit_cast(u32, f);
  u32 r = (u + 0x7FFFu + ((u >> 16) & 1u)) >> 16;
  return (u16)r;
}
DEV float bf2f(u16 v){
  u32 x = ((u32)v) << 16;
  return __builtin_bit_cast(float, x);
}
DEV f32x4 mfma16(s16x8 a, s16x8 b, f32x4 c){
  return __builtin_amdgcn_mfma_f32_16x16x32_bf16(a, b, c, 0, 0, 0);
}
DEV s16x8 ld16B(const u16* p){
  return __builtin_bit_cast(s16x8, *(const u32x4*)p);
}
DEV u32 cvt_pk_bf16(float lo, float hi){
  u32 r;
  asm("v_cvt_pk_bf16_f32 %0, %1, %2" : "=v"(r) : "v"(lo), "v"(hi));
  return r;
}
DEV void gload16(const void* g, void* l){
  __builtin_amdgcn_global_load_lds((const ga_u8*)g, (la_u8*)l, 16, 0, 0);
}
DEV int xcd_chunk(int bid, int nwg){
  int q = nwg >> 3, r = nwg & 7;
  int xcd = bid & 7, lin = bid >> 3;
  return (xcd < r ? xcd*(q+1) : r*(q+1) + (xcd-r)*q) + lin;
}

#define BARRIER() __builtin_amdgcn_s_barrier()
#define VMC4()    asm volatile("s_waitcnt vmcnt(4)" ::: "memory")
#define VMC0()    asm volatile("s_waitcnt vmcnt(0)" ::: "memory")

// Problem sizes: B=8 NT=1569 DIM=768 H=12 D=64 BH=96 F=8 NQ=196 M=12552 Nqkv=2304 K=768
// R10: 32x32 MFMA + 64-elem-row LDS tile = 4-way read conflict; keep 16x16x32.
// R12: launch_bounds(256,4) -> VGPR 64 cap -> spills. Use (256,2).
// R15: rule #20 — only compile-time element indices into address-taken vectors.
// R16: both B halves staged in ph1/ph4 (2-phase HBM cover for B).
// R17: manual register-prefetch of K loads REGRESSED — compiler already hoists them.
// R19: frame split into 2 half-blocks (128 q-rows, 2 mt/wave): halve serial chain,
// 1.5x TLP for the latency-bound attention.

// ---------------- prep: fused cvt + both weight transposes ----------------
__global__ __launch_bounds__(256) void k_prep(const float* __restrict__ x, u16* __restrict__ xb,
                                              const float* __restrict__ Wqkv, u16* __restrict__ wqkvT,
                                              const float* __restrict__ Wout, u16* __restrict__ woutT){
  __shared__ float tile[32][33];
  int b = blockIdx.x, tid = threadIdx.x;
  if (b < 2048){
    const int n4 = 12552*768/4;
    for (int i = b*256 + tid; i < n4; i += 2048*256){
      fvec4 v = ((const fvec4*)x)[i];
      u32 lo = (u32)f2bf(v[0]) | ((u32)f2bf(v[1]) << 16);
      u32 hi = (u32)f2bf(v[2]) | ((u32)f2bf(v[3]) << 16);
      ((u32*)xb)[2*i]   = lo;
      ((u32*)xb)[2*i+1] = hi;
    }
    return;
  }
  const float* W; u16* WT; int K, N, bn, bk;
  if (b < 2048 + 1728){
    int bb = b - 2048; W = Wqkv; WT = wqkvT; K = 768; N = 2304;
    bn = (bb % 72) * 32; bk = (bb / 72) * 32;
  } else {
    int bb = b - 3776; W = Wout; WT = woutT; K = 768; N = 768;
    bn = (bb % 24) * 32; bk = (bb / 24) * 32;
  }
  int tx = tid & 31, ty = tid >> 5;
  #pragma unroll
  for (int r = ty; r < 32; r += 8)
    tile[r][tx] = W[(size_t)(bk + r)*N + bn + tx];
  __syncthreads();
  #pragma unroll
  for (int r = ty; r < 32; r += 8)
    WT[(size_t)(bn + r)*K + bk + tx] = f2bf(tile[tx][r]);
}

// ---------------- QKV GEMM, 256x256, 6-phase, B-early staging (R16-verified) ----------------
__global__ __launch_bounds__(512, 2) void gemm_qkv(const u16* __restrict__ A, const u16* __restrict__ BT,
                                                   u16* __restrict__ qout, u16* __restrict__ kout, u16* __restrict__ vout){
  __shared__ u16 sA[2][2][128*64];
  __shared__ u16 sB[2][2][128*64];
  const int M = 12552;
  const int NWG = 50*9;
  int logical = xcd_chunk(blockIdx.x, NWG);
  int bxi = logical % 9, byi = logical / 9;
  int bm = byi * 256, bn = bxi * 256;

  int tid = threadIdx.x;
  int w = tid >> 6, l = tid & 63, l15 = l & 15, l4 = l >> 4;
  int wm = w >> 2, wn = w & 3;
  int swz = (l15 & 7) << 3;

  f32x4 acc[8][4];
  #pragma unroll
  for (int a=0;a<8;a++)
    #pragma unroll
    for (int b=0;b<4;b++) acc[a][b] = (f32x4){0.f,0.f,0.f,0.f};

  auto stageA = [&](int dbuf, int h, int kt){
    #pragma unroll
    for (int i=0;i<2;i++){
      int ci = i*512 + tid;
      int cs = ci ^ ((ci>>3)&7);
      int r = cs>>3, cc = (cs&7)*8;
      int gr = bm + h*128 + r; if (gr >= M) gr = M-1;
      gload16(A + (size_t)gr*768 + kt*64 + cc, &sA[dbuf][h][(i*512 + (w<<6))*8]);
    }
  };
  auto stageB = [&](int dbuf, int h, int kt){
    #pragma unroll
    for (int i=0;i<2;i++){
      int ci = i*512 + tid;
      int cs = ci ^ ((ci>>3)&7);
      int r = cs>>3, cc = (cs&7)*8;
      gload16(BT + (size_t)(bn + h*128 + r)*768 + kt*64 + cc, &sB[dbuf][h][(i*512 + (w<<6))*8]);
    }
  };

  s16x8 af[4][2], bf[4][2];
  #define LDA_(d, mi, kk) ld16B(&sA[d][wm][(((mi)*16 + l15)*64 + (kk)*32 + l4*8) ^ swz])
  #define LDB_(d, ni, kk) ld16B(&sB[d][(wn*64 + (ni)*16 + l15)>>7][((((wn*64 + (ni)*16 + l15)&127))*64 + (kk)*32 + l4*8) ^ swz])
  #define QUAD(MH, NH) do{ \
    __builtin_amdgcn_s_setprio(1); \
    _Pragma("unroll") \
    for (int j=0;j<4;j++){ \
      _Pragma("unroll") \
      for (int n=0;n<2;n++){ \
        acc[(MH)*4+j][(NH)*2+n] = mfma16(af[j][0], bf[(NH)*2+n][0], acc[(MH)*4+j][(NH)*2+n]); \
        acc[(MH)*4+j][(NH)*2+n] = mfma16(af[j][1], bf[(NH)*2+n][1], acc[(MH)*4+j][(NH)*2+n]); \
      } } \
    __builtin_amdgcn_s_setprio(0); }while(0)

  stageA(0,0,0); stageA(0,1,0); stageB(0,0,0); stageB(0,1,0);
  stageA(1,0,1); stageA(1,1,1);
  VMC4();
  BARRIER();

  #pragma unroll 1
  for (int it = 0; it < 6; ++it){
    int kt1 = 2*it + 1;
    bool full = (it < 5);
    #pragma unroll
    for (int j=0;j<4;j++){ af[j][0]=LDA_(0,j,0); af[j][1]=LDA_(0,j,1); }
    #pragma unroll
    for (int n=0;n<2;n++){ bf[n][0]=LDB_(0,n,0); bf[n][1]=LDB_(0,n,1); }
    stageB(1, 0, kt1); stageB(1, 1, kt1);
    BARRIER();
    QUAD(0,0);
    BARRIER();
    #pragma unroll
    for (int n=2;n<4;n++){ bf[n][0]=LDB_(0,n,0); bf[n][1]=LDB_(0,n,1); }
    BARRIER();
    QUAD(0,1);
    BARRIER();
    #pragma unroll
    for (int j=0;j<4;j++){ af[j][0]=LDA_(0,4+j,0); af[j][1]=LDA_(0,4+j,1); }
    if (full){ stageA(0, 0, kt1+1); stageA(0, 1, kt1+1); }
    BARRIER();
    QUAD(1,0); QUAD(1,1);
    if (full) { VMC4(); } else { VMC0(); }
    BARRIER();
    #pragma unroll
    for (int j=0;j<4;j++){ af[j][0]=LDA_(1,j,0); af[j][1]=LDA_(1,j,1); }
    #pragma unroll
    for (int n=0;n<2;n++){ bf[n][0]=LDB_(1,n,0); bf[n][1]=LDB_(1,n,1); }
    if (full){ stageB(0, 0, kt1+1); stageB(0, 1, kt1+1); }
    BARRIER();
    QUAD(0,0);
    BARRIER();
    #pragma unroll
    for (int n=2;n<4;n++){ bf[n][0]=LDB_(1,n,0); bf[n][1]=LDB_(1,n,1); }
    BARRIER();
    QUAD(0,1);
    BARRIER();
    #pragma unroll
    for (int j=0;j<4;j++){ af[j][0]=LDA_(1,4+j,0); af[j][1]=LDA_(1,4+j,1); }
    if (full){ stageA(1, 0, kt1+2); stageA(1, 1, kt1+2); }
    BARRIER();
    QUAD(1,0); QUAD(1,1);
    if (full) VMC4();
    BARRIER();
  }
  #undef LDA_
  #undef LDB_
  #undef QUAD

  int which = bn / 768;
  int h = ((bn - which*768) >> 6) + wn;
  u16* dst  = (which==0) ? qout : ((which==1) ? kout : vout);
  float scale = (which==0) ? 0.125f : 1.f;
  #pragma unroll
  for (int mi=0; mi<8; mi++){
    #pragma unroll
    for (int r=0; r<4; r++){
      int m = bm + wm*128 + mi*16 + l4*4 + r;
      if (m >= M) continue;
      int b = m / 1569, t = m - b*1569;
      u16* drow = dst + ((size_t)(b*12 + h)*1569 + t)*64 + l15;
      #pragma unroll
      for (int n=0; n<4; n++)
        drow[n*16] = f2bf(acc[mi][n][r] * scale);
    }
  }
}

// ---------------- fused attention: frame v8 (0..1535, 2 half-blocks/frame) + cls_a (1536..2207) ----------------
__global__ __launch_bounds__(256, 2) void k_attn(const u16* __restrict__ qb, const u16* __restrict__ kb,
                                                 const u16* __restrict__ vb, u16* __restrict__ ob,
                                                 float* __restrict__ simw, float* __restrict__ bsum,
                                                 float* __restrict__ pvp){
  __shared__ u16 Vt[64][232];
  __shared__ float rs_lds[4][32];

  int blk = blockIdx.x, tid = threadIdx.x;

  if (blk >= 1536){
    // ---- cls_a: e = exp(s-8), partial sums + partial PV ----
    int bb = blk - 1536;
    int c = bb % 7, g = bb / 7;
    __shared__ float qv[64];
    __shared__ float e_lds[256];
    __shared__ float red[256];
    if (tid < 64) qv[tid] = bf2f(qb[(size_t)g*1569*64 + tid]);
    __syncthreads();
    int j = c*256 + tid;
    float e = 0.f;
    if (j < 1569){
      const u16* kr = kb + ((size_t)g*1569 + j)*64;
      float a = 0.f;
      #pragma unroll
      for (int d0 = 0; d0 < 64; d0 += 8){
        u32x4 u = *(const u32x4*)(kr + d0);
        const u16* us = (const u16*)&u;
        #pragma unroll
        for (int i=0;i<8;i++) a += qv[d0+i]*bf2f(us[i]);
      }
      e = __expf(a - 8.f);
      simw[(size_t)g*1569 + j] = e;
    }
    e_lds[tid] = e;
    red[tid] = e; __syncthreads();
    for (int st=128; st>0; st>>=1){ if (tid<st) red[tid] += red[tid+st]; __syncthreads(); }
    if (tid == 0) bsum[g*8 + c] = red[0];
    int d = tid & 63, kk = tid >> 6;
    float a = 0.f;
    for (int jj = kk; jj < 256; jj += 4){
      int jg = c*256 + jj;
      if (jg < 1569) a += e_lds[jj] * bf2f(vb[((size_t)g*1569+jg)*64 + d]);
    }
    red[tid] = a; __syncthreads();
    if (tid < 64) pvp[((size_t)g*7 + c)*64 + tid] = red[tid]+red[tid+64]+red[tid+128]+red[tid+192];
    return;
  }

  // ---- frame attention v8: half-frame blocks (rows half*128 .. half*128+127) ----
  int g = blk >> 1, half = blk & 1;
  int bh = g >> 3, fi = g & 7;
  int w = tid >> 6, l = tid & 63;
  int l15 = l & 15, l4 = l >> 4;

  const u16* qg = qb + ((size_t)bh*1569 + 1 + fi*196)*64;
  const u16* kg = kb + (size_t)bh*1569*64;
  const u16* vg = vb + (size_t)bh*1569*64;

  {
    int jj = tid >> 3, c = (tid & 7)*8;
    #pragma unroll
    for (int base = 0; base < 224; base += 32){
      int j = base + jj;
      u32x4 vv = {0,0,0,0};
      if (j < 197){
        int t = (j == 0) ? 0 : (1 + fi*196 + j - 1);
        vv = *(const u32x4*)(vg + (size_t)t*64 + c);
      }
      int jl = j & 31;
      int col = (j & ~31) + ((jl>>2)&3)*8 + (jl>>4)*4 + (jl&3);
      const u16* vp = (const u16*)&vv;
      #pragma unroll
      for (int i=0;i<8;i++) Vt[c+i][col] = vp[i];
    }
  }

  s16x8 qf[2][2];
  #pragma unroll
  for (int mt=0; mt<2; mt++){
    int row = half*128 + w*32 + mt*16 + l15;
    #pragma unroll
    for (int kk=0; kk<2; kk++){
      if (row < 196) qf[mt][kk] = ld16B(qg + (size_t)row*64 + kk*32 + l4*8);
      else { u32x4 z = {0,0,0,0}; qf[mt][kk] = __builtin_bit_cast(s16x8, z); }
    }
  }

  f32x4 acc[2][4];
  float rsum[2] = {0.f, 0.f};
  #pragma unroll
  for (int a=0;a<2;a++)
    #pragma unroll
    for (int b=0;b<4;b++) acc[a][b] = (f32x4){0.f,0.f,0.f,0.f};

  __syncthreads();   // Vt ready

  #pragma unroll
  for (int ck = 0; ck < 7; ck++){
    int r0 = ck*32 + l15;
    int r1 = r0 + 16;
    int c0 = (r0 < 197 ? r0 : 196);
    int c1 = (r1 < 197 ? r1 : 196);
    int t0 = (r0 == 0) ? 0 : (1 + fi*196 + c0 - 1);
    int t1 = 1 + fi*196 + c1 - 1;
    s16x8 kf0[2], kf1[2];
    #pragma unroll
    for (int kk=0; kk<2; kk++){
      kf0[kk] = ld16B(kg + (size_t)t0*64 + kk*32 + l4*8);
      kf1[kk] = ld16B(kg + (size_t)t1*64 + kk*32 + l4*8);
    }
    s16x8 vf[4];
    #pragma unroll
    for (int ntd=0; ntd<4; ntd++) vf[ntd] = ld16B(&Vt[ntd*16 + l15][ck*32 + l4*8]);
    int kbase = ck*32 + l4*4;

    #define QKPAIR(m, d0, d1) do{ \
      __builtin_amdgcn_s_setprio(1); \
      d0 = (f32x4){0.f,0.f,0.f,0.f}; d1 = (f32x4){0.f,0.f,0.f,0.f}; \
      d0 = mfma16(kf0[0], qf[m][0], d0); \
      d0 = mfma16(kf0[1], qf[m][1], d0); \
      d1 = mfma16(kf1[0], qf[m][0], d1); \
      d1 = mfma16(kf1[1], qf[m][1], d1); \
      __builtin_amdgcn_s_setprio(0); }while(0)

    f32x4 sc0, sc1, nx0, nx1;
    QKPAIR(0, sc0, sc1);
    #pragma unroll
    for (int mt=0; mt<2; mt++){
      if (mt < 1) QKPAIR(mt+1, nx0, nx1);
      float p[8];
      #pragma unroll
      for (int r=0; r<4; r++){
        p[r]   = (kbase + r      < 197) ? __expf(sc0[r] - 8.f) : 0.f;
        p[4+r] = (kbase + 16 + r < 197) ? __expf(sc1[r] - 8.f) : 0.f;
      }
      rsum[mt] += ((p[0]+p[1])+(p[2]+p[3])) + ((p[4]+p[5])+(p[6]+p[7]));
      u32x4 pw;
      pw[0] = cvt_pk_bf16(p[0], p[1]);
      pw[1] = cvt_pk_bf16(p[2], p[3]);
      pw[2] = cvt_pk_bf16(p[4], p[5]);
      pw[3] = cvt_pk_bf16(p[6], p[7]);
      s16x8 pa = __builtin_bit_cast(s16x8, pw);
      __builtin_amdgcn_s_setprio(1);
      #pragma unroll
      for (int ntd=0; ntd<4; ntd++)
        acc[mt][ntd] = mfma16(pa, vf[ntd], acc[mt][ntd]);
      __builtin_amdgcn_s_setprio(0);
      sc0 = nx0; sc1 = nx1;
    }
    #undef QKPAIR
  }

  #pragma unroll
  for (int mt=0; mt<2; mt++){
    float rs = rsum[mt];
    rs += __shfl_xor(rs, 16);
    rs += __shfl_xor(rs, 32);
    rs_lds[w][mt*16 + l15] = rs;
  }

  u16* og = ob + ((size_t)bh*1569 + 1 + fi*196)*64;
  #pragma unroll
  for (int mt=0; mt<2; mt++){
    #pragma unroll
    for (int r=0; r<4; r++){
      int row = half*128 + w*32 + mt*16 + l4*4 + r;
      if (row < 196){
        float inv = 1.f / rs_lds[w][mt*16 + l4*4 + r];
        #pragma unroll
        for (int ntd=0; ntd<4; ntd++)
          og[(size_t)row*64 + ntd*16 + l15] = f2bf(acc[mt][ntd][r] * inv);
      }
    }
  }
}

// cls_b (672 blocks): normalize chunk -> attn (output #1); c==0 blocks also reduce PV
__global__ __launch_bounds__(256) void cls_b(const float* __restrict__ simw, const float* __restrict__ bsum,
                                             const float* __restrict__ pvp, float* __restrict__ attn,
                                             u16* __restrict__ ob){
  int bb = blockIdx.x;
  int c = bb % 7, g = bb / 7;
  int tid = threadIdx.x;
  float s = 0.f;
  #pragma unroll
  for (int cc=0;cc<7;cc++) s += bsum[g*8+cc];
  float inv = 1.f/s;
  int j = c*256 + tid;
  if (j < 1569)
    attn[(size_t)g*1569+j] = simw[(size_t)g*1569+j]*inv;
  if (c == 0 && tid < 64){
    float a = 0.f;
    #pragma unroll
    for (int cc=0;cc<7;cc++) a += pvp[((size_t)g*7+cc)*64 + tid];
    ob[(size_t)g*1569*64 + tid] = f2bf(a*inv);
  }
}

// ---------------- out GEMM, 256x256, 6-phase, B-early staging (R16-verified) ----------------
__global__ __launch_bounds__(512, 2) void gemm_out(const u16* __restrict__ AO, const u16* __restrict__ BT,
                                                   const float* __restrict__ bias, float* __restrict__ C){
  __shared__ u16 sA[2][2][128*64];
  __shared__ u16 sB[2][2][128*64];
  const int M = 12552;
  const int NWG = 50*3;
  int logical = xcd_chunk(blockIdx.x, NWG);
  int bxi = logical % 3, byi = logical / 3;
  int bm = byi * 256, bn = bxi * 256;

  int tid = threadIdx.x;
  int w = tid >> 6, l = tid & 63, l15 = l & 15, l4 = l >> 4;
  int wm = w >> 2, wn = w & 3;
  int swz = (l15 & 7) << 3;

  f32x4 acc[8][4];
  #pragma unroll
  for (int a=0;a<8;a++)
    #pragma unroll
    for (int b=0;b<4;b++) acc[a][b] = (f32x4){0.f,0.f,0.f,0.f};

  auto stageA = [&](int dbuf, int h, int kt){
    #pragma unroll
    for (int i=0;i<2;i++){
      int ci = i*512 + tid;
      int cs = ci ^ ((ci>>3)&7);
      int r = cs>>3, cc = (cs&7)*8;
      int gr = bm + h*128 + r; if (gr >= M) gr = M-1;
      int b = gr / 1569, t = gr - b*1569;
      gload16(AO + ((size_t)(b*12 + kt)*1569 + t)*64 + cc, &sA[dbuf][h][(i*512 + (w<<6))*8]);
    }
  };
  auto stageB = [&](int dbuf, int h, int kt){
    #pragma unroll
    for (int i=0;i<2;i++){
      int ci = i*512 + tid;
      int cs = ci ^ ((ci>>3)&7);
      int r = cs>>3, cc = (cs&7)*8;
      gload16(BT + (size_t)(bn + h*128 + r)*768 + kt*64 + cc, &sB[dbuf][h][(i*512 + (w<<6))*8]);
    }
  };

  s16x8 af[4][2], bf[4][2];
  #define LDA_(d, mi, kk) ld16B(&sA[d][wm][(((mi)*16 + l15)*64 + (kk)*32 + l4*8) ^ swz])
  #define LDB_(d, ni, kk) ld16B(&sB[d][(wn*64 + (ni)*16 + l15)>>7][((((wn*64 + (ni)*16 + l15)&127))*64 + (kk)*32 + l4*8) ^ swz])
  #define QUAD(MH, NH) do{ \
    __builtin_amdgcn_s_setprio(1); \
    _Pragma("unroll") \
    for (int j=0;j<4;j++){ \
      _Pragma("unroll") \
      for (int n=0;n<2;n++){ \
        acc[(MH)*4+j][(NH)*2+n] = mfma16(af[j][0], bf[(NH)*2+n][0], acc[(MH)*4+j][(NH)*2+n]); \
        acc[(MH)*4+j][(NH)*2+n] = mfma16(af[j][1], bf[(NH)*2+n][1], acc[(MH)*4+j][(NH)*2+n]); \
      } } \
    __builtin_amdgcn_s_setprio(0); }while(0)

  stageA(0,0,0); stageA(0,1,0); stageB(0,0,0); stageB(0,1,0);
  stageA(1,0,1); stageA(1,1,1);
  VMC4();
  BARRIER();

  #pragma unroll 1
  for (int it = 0; it < 6; ++it){
    int kt1 = 2*it + 1;
    bool full = (it < 5);
    #pragma unroll
    for (int j=0;j<4;j++){ af[j][0]=LDA_(0,j,0); af[j][1]=LDA_(0,j,1); }
    #pragma unroll
    for (int n=0;n<2;n++){ bf[n][0]=LDB_(0,n,0); bf[n][1]=LDB_(0,n,1); }
    stageB(1, 0, kt1); stageB(1, 1, kt1);
    BARRIER();
    QUAD(0,0);
    BARRIER();
    #pragma unroll
    for (int n=2;n<4;n++){ bf[n][0]=LDB_(0,n,0); bf[n][1]=LDB_(0,n,1); }
    BARRIER();
    QUAD(0,1);
    BARRIER();
    #pragma unroll
    for (int j=0;j<4;j++){ af[j][0]=LDA_(0,4+j,0); af[j][1]=LDA_(0,4+j,1); }
    if (full){ stageA(0, 0, kt1+1); stageA(0, 1, kt1+1); }
    BARRIER();
    QUAD(1,0); QUAD(1,1);
    if (full) { VMC4(); } else { VMC0(); }
    BARRIER();
    #pragma unroll
    for (int j=0;j<4;j++){ af[j][0]=LDA_(1,j,0); af[j][1]=LDA_(1,j,1); }
    #pragma unroll
    for (int n=0;n<2;n++){ bf[n][0]=LDB_(1,n,0); bf[n][1]=LDB_(1,n,1); }
    if (full){ stageB(0, 0, kt1+1); stageB(0, 1, kt1+1); }
    BARRIER();
    QUAD(0,0);
    BARRIER();
    #pragma unroll
    for (int n=2;n<4;n++){ bf[n][0]=LDB_(1,n,0); bf[n][1]=LDB_(1,n,1); }
    BARRIER();
    QUAD(0,1);
    BARRIER();
    #pragma unroll
    for (int j=0;j<4;j++){ af[j][0]=LDA_(1,4+j,0); af[j][1]=LDA_(1,4+j,1); }
    if (full){ stageA(1, 0, kt1+2); stageA(1, 1, kt1+2); }
    BARRIER();
    QUAD(1,0); QUAD(1,1);
    if (full) VMC4();
    BARRIER();
  }
  #undef LDA_
  #undef LDB_
  #undef QUAD

  int n0 = bn + wn*64;
  float bv[4];
  #pragma unroll
  for (int n=0;n<4;n++) bv[n] = bias[n0 + n*16 + l15];
  #pragma unroll
  for (int mi=0; mi<8; mi++){
    #pragma unroll
    for (int r=0; r<4; r++){
      int m = bm + wm*128 + mi*16 + l4*4 + r;
      if (m >= M) continue;
      float* crow = C + (size_t)m*768 + n0 + l15;
      #pragma unroll
      for (int n=0; n<4; n++)
        crow[n*16] = acc[mi][n][r] + bv[n];
    }
  }
}

extern "C" void kernel_launch(void* const* d_in, const int* in_sizes, int n_in,
                              void* d_out, int out_size, void* d_ws, size_t ws_size,
                              hipStream_t stream){
  (void)in_sizes; (void)n_in; (void)out_size;
  const float* x    = (const float*)d_in[0];
  const float* Wqkv = (const float*)d_in[1];
  const float* Wout = (const float*)d_in[2];
  const float* bout = (const float*)d_in[3];
  float* out0 = (float*)d_out;
  float* out1 = out0 + (size_t)12552*768;   // cls_attn (96*1569)

  char* ws = (char*)d_ws;
  size_t off = 0;
  auto alloc = [&](size_t bytes)->char*{
    char* p = ws + off;
    off += (bytes + 255) & ~(size_t)255;
    return p;
  };
  u16* xb    = (u16*)alloc((size_t)12552*768*2);
  u16* wqkvT = (u16*)alloc((size_t)2304*768*2);
  u16* woutT = (u16*)alloc((size_t)768*768*2);
  u16* qb    = (u16*)alloc((size_t)96*1569*64*2);
  u16* kbuf  = (u16*)alloc((size_t)96*1569*64*2);
  u16* vbuf  = (u16*)alloc((size_t)96*1569*64*2);
  u16* ao    = (u16*)alloc((size_t)96*1569*64*2);
  float* simw = (float*)alloc((size_t)96*1569*4);
  float* bsum = (float*)alloc((size_t)96*8*4);
  float* pvp  = (float*)alloc((size_t)96*7*64*4);
  if (off > ws_size) return;

  k_prep<<<4352, 256, 0, stream>>>(x, xb, Wqkv, wqkvT, Wout, woutT);
  gemm_qkv<<<50*9, 512, 0, stream>>>(xb, wqkvT, qb, kbuf, vbuf);
  k_attn<<<1536 + 672, 256, 0, stream>>>(qb, kbuf, vbuf, ao, simw, bsum, pvp);
  cls_b<<<672, 256, 0, stream>>>(simw, bsum, pvp, out1, ao);
  gemm_out<<<50*3, 512, 0, stream>>>(ao, woutT, bout, out0);
}

// Round 20
// 152.951 us; speedup vs baseline: 1.0586x; 1.0586x over previous
//
#include <hip/hip_runtime.h>

typedef unsigned short u16;
typedef unsigned int u32;
typedef __attribute__((ext_vector_type(8))) short s16x8;   // 8 bf16 (4 VGPR) MFMA frag
typedef __attribute__((ext_vector_type(4))) float f32x4;
typedef __attribute__((ext_vector_type(4))) u32 u32x4;
typedef __attribute__((ext_vector_type(4))) float fvec4;

#define DEV static __device__ __forceinline__

typedef __attribute__((address_space(1))) unsigned char ga_u8;
typedef __attribute__((address_space(3))) unsigned char la_u8;

DEV u16 f2bf(float f){
  u32 u = __builtin_bit_cast(u32, f);
  u32 r = (u + 0x7FFFu + ((u >> 16) & 1u)) >> 16;
  return (u16)r;
}
DEV float bf2f(u16 v){
  u32 x = ((u32)v) << 16;
  return __builtin_bit_cast(float, x);
}
DEV f32x4 mfma16(s16x8 a, s16x8 b, f32x4 c){
  return __builtin_amdgcn_mfma_f32_16x16x32_bf16(a, b, c, 0, 0, 0);
}
DEV s16x8 ld16B(const u16* p){
  return __builtin_bit_cast(s16x8, *(const u32x4*)p);
}
DEV u32 cvt_pk_bf16(float lo, float hi){
  u32 r;
  asm("v_cvt_pk_bf16_f32 %0, %1, %2" : "=v"(r) : "v"(lo), "v"(hi));
  return r;
}
DEV void gload16(const void* g, void* l){
  __builtin_amdgcn_global_load_lds((const ga_u8*)g, (la_u8*)l, 16, 0, 0);
}
DEV int xcd_chunk(int bid, int nwg){
  int q = nwg >> 3, r = nwg & 7;
  int xcd = bid & 7, lin = bid >> 3;
  return (xcd < r ? xcd*(q+1) : r*(q+1) + (xcd-r)*q) + lin;
}

#define BARRIER() __builtin_amdgcn_s_barrier()
#define VMC4()    asm volatile("s_waitcnt vmcnt(4)" ::: "memory")
#define VMC0()    asm volatile("s_waitcnt vmcnt(0)" ::: "memory")

// Problem sizes: B=8 NT=1569 DIM=768 H=12 D=64 BH=96 F=8 NQ=196 M=12552 Nqkv=2304 K=768
// Final configuration (R18-verified, 153.3 us, reproduced twice):
// R10: 32x32 MFMA + 64-elem-row LDS tile = 4-way read conflict; keep 16x16x32.
// R12: launch_bounds(256,4) -> VGPR 64 cap -> spills. Use (256,2).
// R15: rule #20 — only compile-time element indices into address-taken vectors.
// R16: both B halves staged in ph1/ph4 (2-phase HBM cover for B).
// R17: manual register-prefetch of K loads REGRESSED — compiler already hoists them.
// R19: half-frame split REGRESSED — per-block V-staging cost dominates; VGPR caps TLP.

// ---------------- prep: fused cvt + both weight transposes ----------------
__global__ __launch_bounds__(256) void k_prep(const float* __restrict__ x, u16* __restrict__ xb,
                                              const float* __restrict__ Wqkv, u16* __restrict__ wqkvT,
                                              const float* __restrict__ Wout, u16* __restrict__ woutT){
  __shared__ float tile[32][33];
  int b = blockIdx.x, tid = threadIdx.x;
  if (b < 2048){
    const int n4 = 12552*768/4;
    for (int i = b*256 + tid; i < n4; i += 2048*256){
      fvec4 v = ((const fvec4*)x)[i];
      u32 lo = (u32)f2bf(v[0]) | ((u32)f2bf(v[1]) << 16);
      u32 hi = (u32)f2bf(v[2]) | ((u32)f2bf(v[3]) << 16);
      ((u32*)xb)[2*i]   = lo;
      ((u32*)xb)[2*i+1] = hi;
    }
    return;
  }
  const float* W; u16* WT; int K, N, bn, bk;
  if (b < 2048 + 1728){
    int bb = b - 2048; W = Wqkv; WT = wqkvT; K = 768; N = 2304;
    bn = (bb % 72) * 32; bk = (bb / 72) * 32;
  } else {
    int bb = b - 3776; W = Wout; WT = woutT; K = 768; N = 768;
    bn = (bb % 24) * 32; bk = (bb / 24) * 32;
  }
  int tx = tid & 31, ty = tid >> 5;
  #pragma unroll
  for (int r = ty; r < 32; r += 8)
    tile[r][tx] = W[(size_t)(bk + r)*N + bn + tx];
  __syncthreads();
  #pragma unroll
  for (int r = ty; r < 32; r += 8)
    WT[(size_t)(bn + r)*K + bk + tx] = f2bf(tile[tx][r]);
}

// ---------------- QKV GEMM, 256x256, 6-phase, B-early staging (R16-verified) ----------------
__global__ __launch_bounds__(512, 2) void gemm_qkv(const u16* __restrict__ A, const u16* __restrict__ BT,
                                                   u16* __restrict__ qout, u16* __restrict__ kout, u16* __restrict__ vout){
  __shared__ u16 sA[2][2][128*64];
  __shared__ u16 sB[2][2][128*64];
  const int M = 12552;
  const int NWG = 50*9;
  int logical = xcd_chunk(blockIdx.x, NWG);
  int bxi = logical % 9, byi = logical / 9;
  int bm = byi * 256, bn = bxi * 256;

  int tid = threadIdx.x;
  int w = tid >> 6, l = tid & 63, l15 = l & 15, l4 = l >> 4;
  int wm = w >> 2, wn = w & 3;
  int swz = (l15 & 7) << 3;

  f32x4 acc[8][4];
  #pragma unroll
  for (int a=0;a<8;a++)
    #pragma unroll
    for (int b=0;b<4;b++) acc[a][b] = (f32x4){0.f,0.f,0.f,0.f};

  auto stageA = [&](int dbuf, int h, int kt){
    #pragma unroll
    for (int i=0;i<2;i++){
      int ci = i*512 + tid;
      int cs = ci ^ ((ci>>3)&7);
      int r = cs>>3, cc = (cs&7)*8;
      int gr = bm + h*128 + r; if (gr >= M) gr = M-1;
      gload16(A + (size_t)gr*768 + kt*64 + cc, &sA[dbuf][h][(i*512 + (w<<6))*8]);
    }
  };
  auto stageB = [&](int dbuf, int h, int kt){
    #pragma unroll
    for (int i=0;i<2;i++){
      int ci = i*512 + tid;
      int cs = ci ^ ((ci>>3)&7);
      int r = cs>>3, cc = (cs&7)*8;
      gload16(BT + (size_t)(bn + h*128 + r)*768 + kt*64 + cc, &sB[dbuf][h][(i*512 + (w<<6))*8]);
    }
  };

  s16x8 af[4][2], bf[4][2];
  #define LDA_(d, mi, kk) ld16B(&sA[d][wm][(((mi)*16 + l15)*64 + (kk)*32 + l4*8) ^ swz])
  #define LDB_(d, ni, kk) ld16B(&sB[d][(wn*64 + (ni)*16 + l15)>>7][((((wn*64 + (ni)*16 + l15)&127))*64 + (kk)*32 + l4*8) ^ swz])
  #define QUAD(MH, NH) do{ \
    __builtin_amdgcn_s_setprio(1); \
    _Pragma("unroll") \
    for (int j=0;j<4;j++){ \
      _Pragma("unroll") \
      for (int n=0;n<2;n++){ \
        acc[(MH)*4+j][(NH)*2+n] = mfma16(af[j][0], bf[(NH)*2+n][0], acc[(MH)*4+j][(NH)*2+n]); \
        acc[(MH)*4+j][(NH)*2+n] = mfma16(af[j][1], bf[(NH)*2+n][1], acc[(MH)*4+j][(NH)*2+n]); \
      } } \
    __builtin_amdgcn_s_setprio(0); }while(0)

  stageA(0,0,0); stageA(0,1,0); stageB(0,0,0); stageB(0,1,0);
  stageA(1,0,1); stageA(1,1,1);
  VMC4();
  BARRIER();

  #pragma unroll 1
  for (int it = 0; it < 6; ++it){
    int kt1 = 2*it + 1;
    bool full = (it < 5);
    #pragma unroll
    for (int j=0;j<4;j++){ af[j][0]=LDA_(0,j,0); af[j][1]=LDA_(0,j,1); }
    #pragma unroll
    for (int n=0;n<2;n++){ bf[n][0]=LDB_(0,n,0); bf[n][1]=LDB_(0,n,1); }
    stageB(1, 0, kt1); stageB(1, 1, kt1);
    BARRIER();
    QUAD(0,0);
    BARRIER();
    #pragma unroll
    for (int n=2;n<4;n++){ bf[n][0]=LDB_(0,n,0); bf[n][1]=LDB_(0,n,1); }
    BARRIER();
    QUAD(0,1);
    BARRIER();
    #pragma unroll
    for (int j=0;j<4;j++){ af[j][0]=LDA_(0,4+j,0); af[j][1]=LDA_(0,4+j,1); }
    if (full){ stageA(0, 0, kt1+1); stageA(0, 1, kt1+1); }
    BARRIER();
    QUAD(1,0); QUAD(1,1);
    if (full) { VMC4(); } else { VMC0(); }
    BARRIER();
    #pragma unroll
    for (int j=0;j<4;j++){ af[j][0]=LDA_(1,j,0); af[j][1]=LDA_(1,j,1); }
    #pragma unroll
    for (int n=0;n<2;n++){ bf[n][0]=LDB_(1,n,0); bf[n][1]=LDB_(1,n,1); }
    if (full){ stageB(0, 0, kt1+1); stageB(0, 1, kt1+1); }
    BARRIER();
    QUAD(0,0);
    BARRIER();
    #pragma unroll
    for (int n=2;n<4;n++){ bf[n][0]=LDB_(1,n,0); bf[n][1]=LDB_(1,n,1); }
    BARRIER();
    QUAD(0,1);
    BARRIER();
    #pragma unroll
    for (int j=0;j<4;j++){ af[j][0]=LDA_(1,4+j,0); af[j][1]=LDA_(1,4+j,1); }
    if (full){ stageA(1, 0, kt1+2); stageA(1, 1, kt1+2); }
    BARRIER();
    QUAD(1,0); QUAD(1,1);
    if (full) VMC4();
    BARRIER();
  }
  #undef LDA_
  #undef LDB_
  #undef QUAD

  int which = bn / 768;
  int h = ((bn - which*768) >> 6) + wn;
  u16* dst  = (which==0) ? qout : ((which==1) ? kout : vout);
  float scale = (which==0) ? 0.125f : 1.f;
  #pragma unroll
  for (int mi=0; mi<8; mi++){
    #pragma unroll
    for (int r=0; r<4; r++){
      int m = bm + wm*128 + mi*16 + l4*4 + r;
      if (m >= M) continue;
      int b = m / 1569, t = m - b*1569;
      u16* drow = dst + ((size_t)(b*12 + h)*1569 + t)*64 + l15;
      #pragma unroll
      for (int n=0; n<4; n++)
        drow[n*16] = f2bf(acc[mi][n][r] * scale);
    }
  }
}

// ---------------- fused attention: frame v6 (0..767) + cls_a (768..1439) ----------------
__global__ __launch_bounds__(256, 2) void k_attn(const u16* __restrict__ qb, const u16* __restrict__ kb,
                                                 const u16* __restrict__ vb, u16* __restrict__ ob,
                                                 float* __restrict__ simw, float* __restrict__ bsum,
                                                 float* __restrict__ pvp){
  __shared__ u16 Vt[64][232];
  __shared__ float rs_lds[4][64];

  int blk = blockIdx.x, tid = threadIdx.x;

  if (blk >= 768){
    // ---- cls_a: e = exp(s-8), partial sums + partial PV ----
    int bb = blk - 768;
    int c = bb % 7, g = bb / 7;
    __shared__ float qv[64];
    __shared__ float e_lds[256];
    __shared__ float red[256];
    if (tid < 64) qv[tid] = bf2f(qb[(size_t)g*1569*64 + tid]);
    __syncthreads();
    int j = c*256 + tid;
    float e = 0.f;
    if (j < 1569){
      const u16* kr = kb + ((size_t)g*1569 + j)*64;
      float a = 0.f;
      #pragma unroll
      for (int d0 = 0; d0 < 64; d0 += 8){
        u32x4 u = *(const u32x4*)(kr + d0);
        const u16* us = (const u16*)&u;
        #pragma unroll
        for (int i=0;i<8;i++) a += qv[d0+i]*bf2f(us[i]);
      }
      e = __expf(a - 8.f);
      simw[(size_t)g*1569 + j] = e;
    }
    e_lds[tid] = e;
    red[tid] = e; __syncthreads();
    for (int st=128; st>0; st>>=1){ if (tid<st) red[tid] += red[tid+st]; __syncthreads(); }
    if (tid == 0) bsum[g*8 + c] = red[0];
    int d = tid & 63, kk = tid >> 6;
    float a = 0.f;
    for (int jj = kk; jj < 256; jj += 4){
      int jg = c*256 + jj;
      if (jg < 1569) a += e_lds[jj] * bf2f(vb[((size_t)g*1569+jg)*64 + d]);
    }
    red[tid] = a; __syncthreads();
    if (tid < 64) pvp[((size_t)g*7 + c)*64 + tid] = red[tid]+red[tid+64]+red[tid+128]+red[tid+192];
    return;
  }

  // ---- frame attention v6 (R15/R16-verified): K from global, compile-time Vt staging, T15 ----
  int g = blk;
  int bh = g >> 3, fi = g & 7;
  int w = tid >> 6, l = tid & 63;
  int l15 = l & 15, l4 = l >> 4;

  const u16* qg = qb + ((size_t)bh*1569 + 1 + fi*196)*64;
  const u16* kg = kb + (size_t)bh*1569*64;
  const u16* vg = vb + (size_t)bh*1569*64;

  {
    int jj = tid >> 3, c = (tid & 7)*8;
    #pragma unroll
    for (int base = 0; base < 224; base += 32){
      int j = base + jj;
      u32x4 vv = {0,0,0,0};
      if (j < 197){
        int t = (j == 0) ? 0 : (1 + fi*196 + j - 1);
        vv = *(const u32x4*)(vg + (size_t)t*64 + c);
      }
      int jl = j & 31;
      int col = (j & ~31) + ((jl>>2)&3)*8 + (jl>>4)*4 + (jl&3);
      const u16* vp = (const u16*)&vv;
      #pragma unroll
      for (int i=0;i<8;i++) Vt[c+i][col] = vp[i];
    }
  }

  s16x8 qf[4][2];
  #pragma unroll
  for (int mt=0; mt<4; mt++){
    int row = w*64 + mt*16 + l15;
    #pragma unroll
    for (int kk=0; kk<2; kk++){
      if (row < 196) qf[mt][kk] = ld16B(qg + (size_t)row*64 + kk*32 + l4*8);
      else { u32x4 z = {0,0,0,0}; qf[mt][kk] = __builtin_bit_cast(s16x8, z); }
    }
  }

  f32x4 acc[4][4];
  float rsum[4] = {0.f, 0.f, 0.f, 0.f};
  #pragma unroll
  for (int a=0;a<4;a++)
    #pragma unroll
    for (int b=0;b<4;b++) acc[a][b] = (f32x4){0.f,0.f,0.f,0.f};

  __syncthreads();

  #pragma unroll
  for (int ck = 0; ck < 7; ck++){
    int r0 = ck*32 + l15;
    int r1 = r0 + 16;
    int c0 = (r0 < 197 ? r0 : 196);
    int c1 = (r1 < 197 ? r1 : 196);
    int t0 = (r0 == 0) ? 0 : (1 + fi*196 + c0 - 1);
    int t1 = 1 + fi*196 + c1 - 1;
    s16x8 kf0[2], kf1[2];
    #pragma unroll
    for (int kk=0; kk<2; kk++){
      kf0[kk] = ld16B(kg + (size_t)t0*64 + kk*32 + l4*8);
      kf1[kk] = ld16B(kg + (size_t)t1*64 + kk*32 + l4*8);
    }
    s16x8 vf[4];
    #pragma unroll
    for (int ntd=0; ntd<4; ntd++) vf[ntd] = ld16B(&Vt[ntd*16 + l15][ck*32 + l4*8]);
    int kbase = ck*32 + l4*4;

    #define QKPAIR(m, d0, d1) do{ \
      __builtin_amdgcn_s_setprio(1); \
      d0 = (f32x4){0.f,0.f,0.f,0.f}; d1 = (f32x4){0.f,0.f,0.f,0.f}; \
      d0 = mfma16(kf0[0], qf[m][0], d0); \
      d0 = mfma16(kf0[1], qf[m][1], d0); \
      d1 = mfma16(kf1[0], qf[m][0], d1); \
      d1 = mfma16(kf1[1], qf[m][1], d1); \
      __builtin_amdgcn_s_setprio(0); }while(0)

    f32x4 sc0, sc1, nx0, nx1;
    QKPAIR(0, sc0, sc1);
    #pragma unroll
    for (int mt=0; mt<4; mt++){
      if (mt < 3) QKPAIR(mt+1, nx0, nx1);
      float p[8];
      #pragma unroll
      for (int r=0; r<4; r++){
        p[r]   = (kbase + r      < 197) ? __expf(sc0[r] - 8.f) : 0.f;
        p[4+r] = (kbase + 16 + r < 197) ? __expf(sc1[r] - 8.f) : 0.f;
      }
      rsum[mt] += ((p[0]+p[1])+(p[2]+p[3])) + ((p[4]+p[5])+(p[6]+p[7]));
      u32x4 pw;
      pw[0] = cvt_pk_bf16(p[0], p[1]);
      pw[1] = cvt_pk_bf16(p[2], p[3]);
      pw[2] = cvt_pk_bf16(p[4], p[5]);
      pw[3] = cvt_pk_bf16(p[6], p[7]);
      s16x8 pa = __builtin_bit_cast(s16x8, pw);
      __builtin_amdgcn_s_setprio(1);
      #pragma unroll
      for (int ntd=0; ntd<4; ntd++)
        acc[mt][ntd] = mfma16(pa, vf[ntd], acc[mt][ntd]);
      __builtin_amdgcn_s_setprio(0);
      sc0 = nx0; sc1 = nx1;
    }
    #undef QKPAIR
  }

  #pragma unroll
  for (int mt=0; mt<4; mt++){
    float rs = rsum[mt];
    rs += __shfl_xor(rs, 16);
    rs += __shfl_xor(rs, 32);
    rs_lds[w][mt*16 + l15] = rs;
  }

  u16* og = ob + ((size_t)bh*1569 + 1 + fi*196)*64;
  #pragma unroll
  for (int mt=0; mt<4; mt++){
    #pragma unroll
    for (int r=0; r<4; r++){
      int row = w*64 + mt*16 + l4*4 + r;
      if (row < 196){
        float inv = 1.f / rs_lds[w][mt*16 + l4*4 + r];
        #pragma unroll
        for (int ntd=0; ntd<4; ntd++)
          og[(size_t)row*64 + ntd*16 + l15] = f2bf(acc[mt][ntd][r] * inv);
      }
    }
  }
}

// cls_b (672 blocks): normalize chunk -> attn (output #1); c==0 blocks also reduce PV
__global__ __launch_bounds__(256) void cls_b(const float* __restrict__ simw, const float* __restrict__ bsum,
                                             const float* __restrict__ pvp, float* __restrict__ attn,
                                             u16* __restrict__ ob){
  int bb = blockIdx.x;
  int c = bb % 7, g = bb / 7;
  int tid = threadIdx.x;
  float s = 0.f;
  #pragma unroll
  for (int cc=0;cc<7;cc++) s += bsum[g*8+cc];
  float inv = 1.f/s;
  int j = c*256 + tid;
  if (j < 1569)
    attn[(size_t)g*1569+j] = simw[(size_t)g*1569+j]*inv;
  if (c == 0 && tid < 64){
    float a = 0.f;
    #pragma unroll
    for (int cc=0;cc<7;cc++) a += pvp[((size_t)g*7+cc)*64 + tid];
    ob[(size_t)g*1569*64 + tid] = f2bf(a*inv);
  }
}

// ---------------- out GEMM, 256x256, 6-phase, B-early staging (R16-verified) ----------------
__global__ __launch_bounds__(512, 2) void gemm_out(const u16* __restrict__ AO, const u16* __restrict__ BT,
                                                   const float* __restrict__ bias, float* __restrict__ C){
  __shared__ u16 sA[2][2][128*64];
  __shared__ u16 sB[2][2][128*64];
  const int M = 12552;
  const int NWG = 50*3;
  int logical = xcd_chunk(blockIdx.x, NWG);
  int bxi = logical % 3, byi = logical / 3;
  int bm = byi * 256, bn = bxi * 256;

  int tid = threadIdx.x;
  int w = tid >> 6, l = tid & 63, l15 = l & 15, l4 = l >> 4;
  int wm = w >> 2, wn = w & 3;
  int swz = (l15 & 7) << 3;

  f32x4 acc[8][4];
  #pragma unroll
  for (int a=0;a<8;a++)
    #pragma unroll
    for (int b=0;b<4;b++) acc[a][b] = (f32x4){0.f,0.f,0.f,0.f};

  auto stageA = [&](int dbuf, int h, int kt){
    #pragma unroll
    for (int i=0;i<2;i++){
      int ci = i*512 + tid;
      int cs = ci ^ ((ci>>3)&7);
      int r = cs>>3, cc = (cs&7)*8;
      int gr = bm + h*128 + r; if (gr >= M) gr = M-1;
      int b = gr / 1569, t = gr - b*1569;
      gload16(AO + ((size_t)(b*12 + kt)*1569 + t)*64 + cc, &sA[dbuf][h][(i*512 + (w<<6))*8]);
    }
  };
  auto stageB = [&](int dbuf, int h, int kt){
    #pragma unroll
    for (int i=0;i<2;i++){
      int ci = i*512 + tid;
      int cs = ci ^ ((ci>>3)&7);
      int r = cs>>3, cc = (cs&7)*8;
      gload16(BT + (size_t)(bn + h*128 + r)*768 + kt*64 + cc, &sB[dbuf][h][(i*512 + (w<<6))*8]);
    }
  };

  s16x8 af[4][2], bf[4][2];
  #define LDA_(d, mi, kk) ld16B(&sA[d][wm][(((mi)*16 + l15)*64 + (kk)*32 + l4*8) ^ swz])
  #define LDB_(d, ni, kk) ld16B(&sB[d][(wn*64 + (ni)*16 + l15)>>7][((((wn*64 + (ni)*16 + l15)&127))*64 + (kk)*32 + l4*8) ^ swz])
  #define QUAD(MH, NH) do{ \
    __builtin_amdgcn_s_setprio(1); \
    _Pragma("unroll") \
    for (int j=0;j<4;j++){ \
      _Pragma("unroll") \
      for (int n=0;n<2;n++){ \
        acc[(MH)*4+j][(NH)*2+n] = mfma16(af[j][0], bf[(NH)*2+n][0], acc[(MH)*4+j][(NH)*2+n]); \
        acc[(MH)*4+j][(NH)*2+n] = mfma16(af[j][1], bf[(NH)*2+n][1], acc[(MH)*4+j][(NH)*2+n]); \
      } } \
    __builtin_amdgcn_s_setprio(0); }while(0)

  stageA(0,0,0); stageA(0,1,0); stageB(0,0,0); stageB(0,1,0);
  stageA(1,0,1); stageA(1,1,1);
  VMC4();
  BARRIER();

  #pragma unroll 1
  for (int it = 0; it < 6; ++it){
    int kt1 = 2*it + 1;
    bool full = (it < 5);
    #pragma unroll
    for (int j=0;j<4;j++){ af[j][0]=LDA_(0,j,0); af[j][1]=LDA_(0,j,1); }
    #pragma unroll
    for (int n=0;n<2;n++){ bf[n][0]=LDB_(0,n,0); bf[n][1]=LDB_(0,n,1); }
    stageB(1, 0, kt1); stageB(1, 1, kt1);
    BARRIER();
    QUAD(0,0);
    BARRIER();
    #pragma unroll
    for (int n=2;n<4;n++){ bf[n][0]=LDB_(0,n,0); bf[n][1]=LDB_(0,n,1); }
    BARRIER();
    QUAD(0,1);
    BARRIER();
    #pragma unroll
    for (int j=0;j<4;j++){ af[j][0]=LDA_(0,4+j,0); af[j][1]=LDA_(0,4+j,1); }
    if (full){ stageA(0, 0, kt1+1); stageA(0, 1, kt1+1); }
    BARRIER();
    QUAD(1,0); QUAD(1,1);
    if (full) { VMC4(); } else { VMC0(); }
    BARRIER();
    #pragma unroll
    for (int j=0;j<4;j++){ af[j][0]=LDA_(1,j,0); af[j][1]=LDA_(1,j,1); }
    #pragma unroll
    for (int n=0;n<2;n++){ bf[n][0]=LDB_(1,n,0); bf[n][1]=LDB_(1,n,1); }
    if (full){ stageB(0, 0, kt1+1); stageB(0, 1, kt1+1); }
    BARRIER();
    QUAD(0,0);
    BARRIER();
    #pragma unroll
    for (int n=2;n<4;n++){ bf[n][0]=LDB_(1,n,0); bf[n][1]=LDB_(1,n,1); }
    BARRIER();
    QUAD(0,1);
    BARRIER();
    #pragma unroll
    for (int j=0;j<4;j++){ af[j][0]=LDA_(1,4+j,0); af[j][1]=LDA_(1,4+j,1); }
    if (full){ stageA(1, 0, kt1+2); stageA(1, 1, kt1+2); }
    BARRIER();
    QUAD(1,0); QUAD(1,1);
    if (full) VMC4();
    BARRIER();
  }
  #undef LDA_
  #undef LDB_
  #undef QUAD

  int n0 = bn + wn*64;
  float bv[4];
  #pragma unroll
  for (int n=0;n<4;n++) bv[n] = bias[n0 + n*16 + l15];
  #pragma unroll
  for (int mi=0; mi<8; mi++){
    #pragma unroll
    for (int r=0; r<4; r++){
      int m = bm + wm*128 + mi*16 + l4*4 + r;
      if (m >= M) continue;
      float* crow = C + (size_t)m*768 + n0 + l15;
      #pragma unroll
      for (int n=0; n<4; n++)
        crow[n*16] = acc[mi][n][r] + bv[n];
    }
  }
}

extern "C" void kernel_launch(void* const* d_in, const int* in_sizes, int n_in,
                              void* d_out, int out_size, void* d_ws, size_t ws_size,
                              hipStream_t stream){
  (void)in_sizes; (void)n_in; (void)out_size;
  const float* x    = (const float*)d_in[0];
  const float* Wqkv = (const float*)d_in[1];
  const float* Wout = (const float*)d_in[2];
  const float* bout = (const float*)d_in[3];
  float* out0 = (float*)d_out;
  float* out1 = out0 + (size_t)12552*768;   // cls_attn (96*1569)

  char* ws = (char*)d_ws;
  size_t off = 0;
  auto alloc = [&](size_t bytes)->char*{
    char* p = ws + off;
    off += (bytes + 255) & ~(size_t)255;
    return p;
  };
  u16* xb    = (u16*)alloc((size_t)12552*768*2);
  u16* wqkvT = (u16*)alloc((size_t)2304*768*2);
  u16* woutT = (u16*)alloc((size_t)768*768*2);
  u16* qb    = (u16*)alloc((size_t)96*1569*64*2);
  u16* kbuf  = (u16*)alloc((size_t)96*1569*64*2);
  u16* vbuf  = (u16*)alloc((size_t)96*1569*64*2);
  u16* ao    = (u16*)alloc((size_t)96*1569*64*2);
  float* simw = (float*)alloc((size_t)96*1569*4);
  float* bsum = (float*)alloc((size_t)96*8*4);
  float* pvp  = (float*)alloc((size_t)96*7*64*4);
  if (off > ws_size) return;

  k_prep<<<4352, 256, 0, stream>>>(x, xb, Wqkv, wqkvT, Wout, woutT);
  gemm_qkv<<<50*9, 512, 0, stream>>>(xb, wqkvT, qb, kbuf, vbuf);
  k_attn<<<1440, 256, 0, stream>>>(qb, kbuf, vbuf, ao, simw, bsum, pvp);
  cls_b<<<672, 256, 0, stream>>>(simw, bsum, pvp, out1, ao);
  gemm_out<<<50*3, 512, 0, stream>>>(ao, woutT, bout, out0);
}